// Round 11
// baseline (719.839 us; speedup 1.0000x reference)
//
#include <hip/hip_runtime.h>
#include <hip/hip_bf16.h>
#include <stdint.h>

#define Bn 64
#define Ln 2048
#define Hn 128
#define Vn 32000
#define THn 256            // 2*H
#define LAMBDA_ (1.0f/2048.0f)
#define CC 32              // scan chunk size
#define NCH (Ln/CC)        // 64 chunks
#define KP  132            // p2 kn_p row stride (uints)
#define KTS 36             // p2 knT row stride (uints)
#define ADT 36             // p2 adT row stride (uints, packed)
#define VS  132            // p2 vp0L row stride (floats)
#define VPW (CC*VS)        // p2 vp0L buffer size
#define GS  36             // p2 Gt row stride
#define GXS 36             // p2 GxT row stride (floats, swizzled vector access)
#define MSR 36             // p2 m_scratch row stride (uints)
#define MSW 576            // p2 m_scratch per-wave size (16*36)
#define HS  132            // p1 h_p/u_p row stride (uints)

typedef short bf16x8 __attribute__((ext_vector_type(8)));
typedef float f32x4  __attribute__((ext_vector_type(4)));

__device__ __forceinline__ float rdlane(float v, int s) {
  return __int_as_float(__builtin_amdgcn_readlane(__float_as_int(v), s));
}

// DPP-based add step: x += dpp_select(x). ctrl is a template param (must be
// an ICE at the builtin call site).
template <int CTRL>
__device__ __forceinline__ float dpp_add(float x) {
  int t = __builtin_amdgcn_update_dpp(0, __float_as_int(x), CTRL, 0xf, 0xf, false);
  return x + __int_as_float(t);
}
// full 64-lane sum, result broadcast via readlane(63)
__device__ __forceinline__ float wave_sum64(float x) {
  x = dpp_add<0x111>(x);   // row_shr:1
  x = dpp_add<0x112>(x);   // row_shr:2
  x = dpp_add<0x114>(x);   // row_shr:4
  x = dpp_add<0x118>(x);   // row_shr:8  -> lane 15 of each row = row sum
  x = dpp_add<0x142>(x);   // row_bcast:15
  x = dpp_add<0x143>(x);   // row_bcast:31 -> lane63 = total
  return rdlane(x, 63);
}

// pack fp32 -> (bf16 hi in low16, bf16 lo in high16), truncation split
__device__ __forceinline__ uint32_t packhl(float x) {
  uint32_t bx = __float_as_uint(x);
  float hf = __uint_as_float(bx & 0xFFFF0000u);
  uint32_t bl = __float_as_uint(x - hf);
  return (bx >> 16) | (bl & 0xFFFF0000u);
}
__device__ __forceinline__ float unpackhl(uint32_t u) {
  return __uint_as_float(u << 16) + __uint_as_float(u & 0xFFFF0000u);
}

struct FragHL { bf16x8 h; bf16x8 l; };
__device__ __forceinline__ FragHL mkfrag(const uint32_t* u) {
  union { uint32_t a[4]; bf16x8 v; } H, L;
  H.a[0] = __builtin_amdgcn_perm(u[1], u[0], 0x05040100u);
  H.a[1] = __builtin_amdgcn_perm(u[3], u[2], 0x05040100u);
  H.a[2] = __builtin_amdgcn_perm(u[5], u[4], 0x05040100u);
  H.a[3] = __builtin_amdgcn_perm(u[7], u[6], 0x05040100u);
  L.a[0] = __builtin_amdgcn_perm(u[1], u[0], 0x07060302u);
  L.a[1] = __builtin_amdgcn_perm(u[3], u[2], 0x07060302u);
  L.a[2] = __builtin_amdgcn_perm(u[5], u[4], 0x07060302u);
  L.a[3] = __builtin_amdgcn_perm(u[7], u[6], 0x07060302u);
  FragHL f; f.h = H.v; f.l = L.v; return f;
}

__device__ __forceinline__ void ld8(const uint32_t* p, uint32_t* u) {
  const uint4 a = *reinterpret_cast<const uint4*>(p);
  const uint4 b = *reinterpret_cast<const uint4*>(p + 4);
  u[0]=a.x; u[1]=a.y; u[2]=a.z; u[3]=a.w;
  u[4]=b.x; u[5]=b.y; u[6]=b.z; u[7]=b.w;
}

__device__ __forceinline__ bf16x8 asbf(uint4 u) {
  union { uint4 a; bf16x8 v; } c; c.a = u; return c.v;
}

__device__ __forceinline__ f32x4 mfma16(bf16x8 a, bf16x8 b, f32x4 c) {
  return __builtin_amdgcn_mfma_f32_16x16x32_bf16(a, b, c, 0, 0, 0);
}

// async global->LDS, width 4 bytes, per-lane global addr, wave-uniform LDS base
__device__ __forceinline__ void gload_lds4(const uint32_t* g, uint32_t* l) {
  __builtin_amdgcn_global_load_lds(
      (const __attribute__((address_space(1))) void*)g,
      (__attribute__((address_space(3))) void*)l, 4, 0, 0);
}

// ---------------------------------------------------------------------------
// p0: pack weights once into fragment-ready hi/lo bf16-pair arrays in ws.
// ---------------------------------------------------------------------------
__global__ __launch_bounds__(256) void p0_pack(
    const float* __restrict__ w1, const float* __restrict__ w2,
    const float* __restrict__ kp, uint32_t* __restrict__ wp)
{
  const int id = blockIdx.x*256 + threadIdx.x;   // pair index, 0..40959
  const float* src; uint32_t *dh, *dl; int p;
  if (id < 16384)      { src = w1; p = id;         dh = wp;         dl = wp+16384; }
  else if (id < 32768) { src = w2; p = id-16384;   dh = wp+32768;   dl = wp+49152; }
  else                 { src = kp; p = id-32768;   dh = wp+65536;   dl = wp+73728; }
  const float x0 = src[2*p], x1 = src[2*p+1];
  const uint32_t b0 = __float_as_uint(x0), b1 = __float_as_uint(x1);
  const float l0f = x0 - __uint_as_float(b0 & 0xFFFF0000u);
  const float l1f = x1 - __uint_as_float(b1 & 0xFFFF0000u);
  dh[p] = (b0 >> 16) | ((b1 >> 16) << 16);
  dl[p] = (__float_as_uint(l0f) >> 16) | ((__float_as_uint(l1f) >> 16) << 16);
}

// ---------------------------------------------------------------------------
// Phase 1 (MFMA, unchanged)
// ---------------------------------------------------------------------------
__global__ __launch_bounds__(256, 2) void p1_fused(
    const int* __restrict__ seq,
    const float* __restrict__ embed_w,
    const uint32_t* __restrict__ wp,
    const float* __restrict__ ff_b1, const float* __restrict__ ff_b2,
    const float* __restrict__ ln_g, const float* __restrict__ ln_b,
    uint32_t* __restrict__ knp_all, float* __restrict__ norm_all)
{
  __shared__ __align__(16) uint32_t h_p[64*HS];   // packed h, later packed hn
  __shared__ __align__(16) uint32_t u_p[64*HS];   // packed u (one 128-col half)
  __shared__ float part1[256], part2[256];
  __shared__ float mul[64], rsl[64];
  __shared__ int sid[64];

  const int tid  = threadIdx.x;
  const int lane = tid & 63;
  const int w    = __builtin_amdgcn_readfirstlane(tid >> 6);
  const int q4   = lane >> 4;
  const int m16  = lane & 15;
  const int tile0 = blockIdx.x * 64;

  const uint32_t* w1h = wp;
  const uint32_t* w1l = wp + 16384;
  const uint32_t* w2h = wp + 32768;
  const uint32_t* w2l = wp + 49152;
  const uint32_t* kph = wp + 65536;
  const uint32_t* kpl = wp + 73728;

  if (tid < 64) sid[tid] = seq[tile0 + tid];
  __syncthreads();

  { // embed gather -> packed h_p[token][feature]
    const int t = tid >> 2, part = tid & 3;
    const float4* erow =
        reinterpret_cast<const float4*>(embed_w + (size_t)sid[t]*Hn) + part*8;
    #pragma unroll
    for (int c = 0; c < 8; ++c) {
      float4 v = erow[c];
      int j = part*32 + c*4;
      h_p[t*HS+j+0] = packhl(v.x); h_p[t*HS+j+1] = packhl(v.y);
      h_p[t*HS+j+2] = packhl(v.z); h_p[t*HS+j+3] = packhl(v.w);
    }
  }
  __syncthreads();

  f32x4 acc2[4][2];
  #pragma unroll
  for (int tt=0;tt<4;++tt)
    #pragma unroll
    for (int ct=0;ct<2;++ct) acc2[tt][ct] = (f32x4){0.f,0.f,0.f,0.f};

  #pragma unroll 1
  for (int ho=0; ho<2; ++ho) {
    #pragma unroll 1
    for (int tt=0; tt<4; ++tt) {
      FragHL fa[4];
      #pragma unroll
      for (int kk=0;kk<4;++kk) {
        uint32_t ua[8];
        ld8(&h_p[(16*tt+m16)*HS + 32*kk + 8*q4], ua);
        fa[kk] = mkfrag(ua);
      }
      #pragma unroll
      for (int ct=0; ct<2; ++ct) {
        const int ob = 128*ho + 32*w + 16*ct;
        f32x4 a = (f32x4){0.f,0.f,0.f,0.f};
        #pragma unroll
        for (int kk=0;kk<4;++kk) {
          const size_t wi = (size_t)(ob+m16)*64 + 16*kk + 4*q4;
          bf16x8 bh = asbf(*reinterpret_cast<const uint4*>(&w1h[wi]));
          bf16x8 bl = asbf(*reinterpret_cast<const uint4*>(&w1l[wi]));
          a = mfma16(fa[kk].h, bh, a);
          a = mfma16(fa[kk].h, bl, a);
          a = mfma16(fa[kk].l, bh, a);
        }
        const float bb = ff_b1[ob + m16];
        #pragma unroll
        for (int reg=0;reg<4;++reg) {
          float uv = fmaxf(a[reg] + bb, 0.f);
          u_p[(16*tt+4*q4+reg)*HS + 32*w + 16*ct + m16] = packhl(uv);
        }
      }
    }
    __syncthreads();
    #pragma unroll 1
    for (int tt=0; tt<4; ++tt) {
      FragHL fu[4];
      #pragma unroll
      for (int kk=0;kk<4;++kk) {
        uint32_t ua[8];
        ld8(&u_p[(16*tt+m16)*HS + 32*kk + 8*q4], ua);
        fu[kk] = mkfrag(ua);
      }
      #pragma unroll
      for (int ct=0; ct<2; ++ct) {
        const int ib = 32*w + 16*ct;
        f32x4 a = acc2[tt][ct];
        #pragma unroll
        for (int kk=0;kk<4;++kk) {
          const size_t wi = (size_t)(ib+m16)*128 + 64*ho + 16*kk + 4*q4;
          bf16x8 bh = asbf(*reinterpret_cast<const uint4*>(&w2h[wi]));
          bf16x8 bl = asbf(*reinterpret_cast<const uint4*>(&w2l[wi]));
          a = mfma16(fu[kk].h, bh, a);
          a = mfma16(fu[kk].h, bl, a);
          a = mfma16(fu[kk].l, bh, a);
        }
        acc2[tt][ct] = a;
      }
    }
    __syncthreads();
  }

  // ---- bias + residual; LN partials ----
  float xx[4][2][4];
  #pragma unroll
  for (int tt=0;tt<4;++tt)
    #pragma unroll
    for (int ct=0;ct<2;++ct) {
      const int col = 32*w + 16*ct + m16;
      const float b2 = ff_b2[col];
      #pragma unroll
      for (int reg=0;reg<4;++reg) {
        const float hval = unpackhl(h_p[(16*tt+4*q4+reg)*HS + col]);
        xx[tt][ct][reg] = acc2[tt][ct][reg] + b2 + hval;
      }
    }
  #pragma unroll
  for (int tt=0;tt<4;++tt)
    #pragma unroll
    for (int reg=0;reg<4;++reg) {
      float s1 = xx[tt][0][reg] + xx[tt][1][reg];
      float s2 = xx[tt][0][reg]*xx[tt][0][reg] + xx[tt][1][reg]*xx[tt][1][reg];
      s1 += __shfl_xor(s1,1); s1 += __shfl_xor(s1,2);
      s1 += __shfl_xor(s1,4); s1 += __shfl_xor(s1,8);
      s2 += __shfl_xor(s2,1); s2 += __shfl_xor(s2,2);
      s2 += __shfl_xor(s2,4); s2 += __shfl_xor(s2,8);
      if (m16==0) {
        part1[w*64 + 16*tt+4*q4+reg] = s1;
        part2[w*64 + 16*tt+4*q4+reg] = s2;
      }
    }
  __syncthreads();
  if (tid < 64) {
    const float mu = (part1[tid]+part1[64+tid]+part1[128+tid]+part1[192+tid])*(1.0f/128.0f);
    const float ms = (part2[tid]+part2[64+tid]+part2[128+tid]+part2[192+tid])*(1.0f/128.0f);
    mul[tid] = mu;
    rsl[tid] = rsqrtf(ms - mu*mu + 1e-5f);
  }
  __syncthreads();

  #pragma unroll
  for (int tt=0;tt<4;++tt)
    #pragma unroll
    for (int ct=0;ct<2;++ct) {
      const int col = 32*w + 16*ct + m16;
      const float g = ln_g[col], bb = ln_b[col];
      #pragma unroll
      for (int reg=0;reg<4;++reg) {
        const int tok = 16*tt+4*q4+reg;
        const float hn = (xx[tt][ct][reg] - mul[tok])*rsl[tok]*g + bb;
        h_p[tok*HS + col] = packhl(hn);
      }
    }
  __syncthreads();

  // ---- k projection ----
  f32x4 ak[4][2];
  #pragma unroll 1
  for (int tt=0;tt<4;++tt) {
    FragHL fh[4];
    #pragma unroll
    for (int kk=0;kk<4;++kk) {
      uint32_t ua[8];
      ld8(&h_p[(16*tt+m16)*HS + 32*kk + 8*q4], ua);
      fh[kk] = mkfrag(ua);
    }
    #pragma unroll
    for (int ct=0;ct<2;++ct) {
      const int ob = 32*w + 16*ct;
      f32x4 a = (f32x4){0.f,0.f,0.f,0.f};
      #pragma unroll
      for (int kk=0;kk<4;++kk) {
        const size_t wi = (size_t)(ob+m16)*64 + 16*kk + 4*q4;
        bf16x8 bh = asbf(*reinterpret_cast<const uint4*>(&kph[wi]));
        bf16x8 bl = asbf(*reinterpret_cast<const uint4*>(&kpl[wi]));
        a = mfma16(fh[kk].h, bh, a);
        a = mfma16(fh[kk].h, bl, a);
        a = mfma16(fh[kk].l, bh, a);
      }
      ak[tt][ct] = a;
    }
  }
  #pragma unroll
  for (int tt=0;tt<4;++tt)
    #pragma unroll
    for (int reg=0;reg<4;++reg) {
      float s = ak[tt][0][reg]*ak[tt][0][reg] + ak[tt][1][reg]*ak[tt][1][reg];
      s += __shfl_xor(s,1); s += __shfl_xor(s,2);
      s += __shfl_xor(s,4); s += __shfl_xor(s,8);
      if (m16==0) part1[w*64 + 16*tt+4*q4+reg] = s;
    }
  __syncthreads();
  if (tid < 64) {
    const float nn = part1[tid]+part1[64+tid]+part1[128+tid]+part1[192+tid];
    const float nrm = sqrtf(nn);
    norm_all[tile0 + tid] = nrm;
    mul[tid] = 1.0f / fmaxf(nrm, 1e-12f);
  }
  __syncthreads();
  #pragma unroll
  for (int tt=0;tt<4;++tt)
    #pragma unroll
    for (int ct=0;ct<2;++ct) {
      const int col = 32*w + 16*ct + m16;
      #pragma unroll
      for (int reg=0;reg<4;++reg) {
        const int tok = 16*tt+4*q4+reg;
        knp_all[(size_t)(tile0+tok)*Hn + col] = packhl(ak[tt][ct][reg]*mul[tok]);
      }
    }
}

// ---------------------------------------------------------------------------
// Phase 2 (r19): split loops + adT/GxT vectorized fragments.
//   r19 vs r18 — continue cutting LDS-pipe instruction count (validated
//   model: b32~5.8cyc, b128~12cyc; corr=3.2k cyc/chunk was the next pole):
//   - adL replaced by adT[h][t^sw(h)] (PACKED u32, single buffer): wave0
//     writes the transposed+packed form (same 2 stores/step + packhl).
//     The AD^T A-fragment (needed by corr(ch) and E(ch+1)) becomes 2
//     aligned b128 reads; built once in corr and CARRIED IN REGS to E.
//   - GxT stride 33->36 + per-row XOR swizzle (col ^ 8*(row&3)): corr's
//     B-rows read as 4 float4 (was 32 scalar b32), <=2-way banks.
//   - corr's msc roundtrip eliminated entirely (msc now vpP-only).
// ---------------------------------------------------------------------------
__global__ __launch_bounds__(768, 3) void p2_scan(
    const uint32_t* __restrict__ knp_all, const float* __restrict__ norm_all,
    float* __restrict__ read_ws)
{
  const int tid  = threadIdx.x;
  const int lane = tid & 63;
  const int wv   = __builtin_amdgcn_readfirstlane(tid >> 6);  // 0..11
  const int q    = lane >> 4;
  const int m    = lane & 15;
  const int b    = blockIdx.x;

  __shared__ __align__(16) uint32_t kn_p[2*CC*KP];  // double-buffered, swizzled
  __shared__ __align__(16) uint32_t knT [128*KTS];  // transposed copy for E
  __shared__ __align__(16) uint32_t adT [128*ADT];  // packed AD^T (single buf)
  __shared__ __align__(16) float    vp0L[2*VPW];    // double-buffered c values
  __shared__ __align__(16) float    Gt  [2*CC*GS];  // double-buffered Gram
  __shared__ __align__(16) float    GxT [CC*GXS];   // GxT[j][s^8*(j&3)]
  __shared__ __align__(16) uint32_t msc [8*MSW];    // vpP transpose scratch
  __shared__ float nrm_l[4*CC];

  const uint32_t* knb = knp_all + (size_t)b*Ln*Hn;
  const float*    nb  = norm_all + (size_t)b*Ln;

  const int swm  = ((m>>3)&3)<<3;         // swizzle for row m (m<16)
  const int swm2 = (((16+m)>>3)&3)<<3;    // swizzle for row 16+m

  { // prologue stage: kn(0)->buf0, kn(1)->buf1 (swizzled), nrm slots 0,1
    if (tid < 256) {
      const int t = tid>>3, g = tid&7;
      const int sw = ((t>>3)&3)<<3;
      const uint4* src = reinterpret_cast<const uint4*>(knb + t*Hn + g*16);
      uint32_t* dstb = &kn_p[t*KP];
      *reinterpret_cast<uint4*>(&dstb[(16*g+0) ^ sw])  = src[0];
      *reinterpret_cast<uint4*>(&dstb[(16*g+4) ^ sw])  = src[1];
      *reinterpret_cast<uint4*>(&dstb[(16*g+8) ^ sw])  = src[2];
      *reinterpret_cast<uint4*>(&dstb[(16*g+12) ^ sw]) = src[3];
    } else if (tid < 512) {
      const int idx = tid-256, t = idx>>3, g = idx&7;
      const int sw = ((t>>3)&3)<<3;
      const uint4* src = reinterpret_cast<const uint4*>(knb + CC*Hn + t*Hn + g*16);
      uint32_t* dstb = &kn_p[CC*KP + t*KP];
      *reinterpret_cast<uint4*>(&dstb[(16*g+0) ^ sw])  = src[0];
      *reinterpret_cast<uint4*>(&dstb[(16*g+4) ^ sw])  = src[1];
      *reinterpret_cast<uint4*>(&dstb[(16*g+8) ^ sw])  = src[2];
      *reinterpret_cast<uint4*>(&dstb[(16*g+12) ^ sw]) = src[3];
    } else if (tid < 512+2*CC) {
      nrm_l[tid-512] = nb[tid-512];
    }
  }
  __syncthreads();

  { // prologue compute: Gram(0) -> Gt[0] (waves 9-11); c(0) (waves 1-8)
    if (wv >= 9) {
      const int gi = wv - 9;                  // 0,1,2 -> (0,0),(0,1)+T,(1,1)
      if (gi < 3) {
        const int ti = (gi==2) ? 1 : 0;
        const int si = (gi==0) ? 0 : 1;
        const int ra = 16*ti+m, rb = 16*si+m;
        const int swa = ((ra>>3)&3)<<3, swb = ((rb>>3)&3)<<3;
        f32x4 g4 = (f32x4){0.f,0.f,0.f,0.f};
        #pragma unroll
        for (int kk=0; kk<4; ++kk) {
          uint32_t ua[8], ub[8];
          ld8(&kn_p[ra*KP + ((32*kk + 8*q) ^ swa)], ua);
          ld8(&kn_p[rb*KP + ((32*kk + 8*q) ^ swb)], ub);
          FragHL fa = mkfrag(ua), fb = mkfrag(ub);
          g4 = mfma16(fa.h, fb.h, g4);
          g4 = mfma16(fa.h, fb.l, g4);
          g4 = mfma16(fa.l, fb.h, g4);
        }
        #pragma unroll
        for (int reg=0; reg<4; ++reg)
          Gt[(16*ti + 4*q + reg)*GS + 16*si + m] = g4[reg];
        if (gi==1) {
          #pragma unroll
          for (int reg=0; reg<4; ++reg)
            Gt[(16*si + m)*GS + 16*ti + 4*q + reg] = g4[reg];
        }
      }
    }
    if (wv >= 1 && wv <= 8) {
      const int h0 = 16*(wv-1);
      const float nr0 = nrm_l[m], nr1 = nrm_l[16+m];
      const uint4 r0 = *reinterpret_cast<const uint4*>(&kn_p[m*KP + ((h0 + 4*q) ^ swm)]);
      const uint4 r1 = *reinterpret_cast<const uint4*>(&kn_p[(16+m)*KP + ((h0 + 4*q) ^ swm2)]);
      const uint32_t* pr0 = &r0.x; const uint32_t* pr1 = &r1.x;
      #pragma unroll
      for (int reg=0; reg<4; ++reg) {
        const int h = h0 + 4*q + reg;
        vp0L[m*VS + h]      = nr0*unpackhl(pr0[reg]);
        vp0L[(16+m)*VS + h] = nr1*unpackhl(pr1[reg]);
      }
    }
  }
  __syncthreads();

  if (wv == 0) {
    // ======================= serial-scan loop =======================
    const int swl = ((lane>>3)&3)<<3;    // adT t-swizzle (same for lane,64+lane)
    #pragma unroll 1
    for (int ch=0; ch<NCH; ++ch) {
      const int cur = ch&1;
      const int sel = ch & 1;
      const uint32_t* knc = &kn_p[cur*CC*KP];

      float ad0[CC], ad1[CC];
      const float* vpR = &vp0L[sel*VPW];
      const float* GtS = &Gt[sel*CC*GS];
      const int lid = lane & 31;
      const float nrmv = nrm_l[(ch&3)*CC + lid];
      float grt = GtS[0*GS + lid];            // 2-deep gr pipeline (3 regs)
      float grn = GtS[1*GS + lid];
      __builtin_amdgcn_s_setprio(1);
      #pragma unroll
      for (int t=0;t<CC;++t) {
        float grn2 = 0.f;
        if (t+2 < CC) grn2 = GtS[(t+2)*GS + lid];
        float a0c0 = vpR[t*VS + lane];        // c0
        float a1c0 = vpR[t*VS + 64 + lane];   // c1
        float a0c1=0.f, a0c2=0.f, a0c3=0.f;
        float a1c1=0.f, a1c2=0.f, a1c3=0.f;
        #pragma unroll
        for (int s=0; s<t; ++s) {                   // static: only s<t emitted
          const float g = rdlane(grt, s);
          switch (s & 3) {
            case 0: a0c0 -= g*ad0[s]; a1c0 -= g*ad1[s]; break;
            case 1: a0c1 -= g*ad0[s]; a1c1 -= g*ad1[s]; break;
            case 2: a0c2 -= g*ad0[s]; a1c2 -= g*ad1[s]; break;
            default:a0c3 -= g*ad0[s]; a1c3 -= g*ad1[s]; break;
          }
        }
        const float acc0 = (a0c0+a0c1)+(a0c2+a0c3);
        const float acc1 = (a1c0+a1c1)+(a1c2+a1c3);
        const float sqt = wave_sum64(acc0*acc0 + acc1*acc1);
        const float nrm = rdlane(nrmv, t);
        if (ch==NCH-1 && t==CC-1) {
          // read = M@q, q = nrm*kn; M.kn = nrm*kn - d
          const int swt = ((t>>3)&3)<<3;
          const float kn0 = unpackhl(knc[t*KP + (lane ^ swt)]);
          const float kn1 = unpackhl(knc[t*KP + ((64+lane) ^ swt)]);
          read_ws[b*Hn + lane]      = nrm*(nrm*kn0 - acc0);
          read_ws[b*Hn + 64 + lane] = nrm*(nrm*kn1 - acc1);
        } else {
          // gate: sqrt(sq) >= 0.4*nrm  <=>  sq >= 0.16*nrm*nrm (uniform)
          const float at = (sqt >= 0.16f*nrm*nrm) ? LAMBDA_ : 0.f;
          ad0[t] = at*acc0; ad1[t] = at*acc1;
          adT[lane*ADT + (t ^ swl)]      = packhl(ad0[t]);
          adT[(64+lane)*ADT + (t ^ swl)] = packhl(ad1[t]);
        }
        grt = grn; grn = grn2;
      }
      __builtin_amdgcn_s_setprio(0);

      __syncthreads();                     // B2
      if (ch==NCH-1) break;
      __syncthreads();                     // B1
    }
  } else if (wv <= 8) {
    // ================= E / vpP / fold / corr / staging =================
    f32x4 Macc[8];
    #pragma unroll
    for (int ct=0; ct<8; ++ct) Macc[ct] = (f32x4){0.f,0.f,0.f,0.f};
    const int h0 = 16*(wv-1);
    FragHL faAD;                           // AD^T fragment carried corr->E
    { uint32_t z[8] = {0,0,0,0,0,0,0,0}; faAD = mkfrag(z); }

    #pragma unroll 1
    for (int ch=0; ch<NCH; ++ch) {
      const int cur = ch&1, nx1 = (ch+1)&1;
      const int sel = ch & 1;
      const uint32_t* knN = &kn_p[nx1*CC*KP];
      const bool havn  = (ch+1 < NCH);
      const bool havn2 = (ch+2 < NCH);

      // nrm prefetch for ch+2 (1 VGPR, wave 4 hi-lanes only)
      float pfn = 0.f;
      if (havn2 && tid >= 288 && tid < 320) pfn = nb[(ch+2)*CC + (tid-288)];

      if (havn) {
        // ---- deferred E(ch-1): Macc += AD(ch-1)^T * Kn_{ch-1} ----
        // A-fragment carried in regs from corr(ch-1); B from knT.
        if (ch >= 1) {
          #pragma unroll
          for (int ct=0; ct<8; ++ct) {
            const int hcol = 16*ct + m;
            const int swz = ((hcol>>3)&3)<<3;
            uint32_t bu[8];
            ld8(&knT[hcol*KTS + (8*q ^ swz)], bu);
            FragHL fb = mkfrag(bu);
            Macc[ct] = mfma16(faAD.h, fb.h, Macc[ct]);
            Macc[ct] = mfma16(faAD.h, fb.l, Macc[ct]);
            Macc[ct] = mfma16(faAD.l, fb.h, Macc[ct]);
          }
        }
        // ---- vpP slice: v = M^{(ch)} * Kn_{ch+1}^T; fold into vp0L[1-sel] ----
        {
          f32x4 v0 = (f32x4){0.f,0.f,0.f,0.f};
          f32x4 v1 = (f32x4){0.f,0.f,0.f,0.f};
          uint32_t* mybase = &msc[(wv-1)*MSW];
          #pragma unroll
          for (int kk=0; kk<4; ++kk) {
            #pragma unroll
            for (int c2=0; c2<2; ++c2) {
              const int ct = 2*kk + c2;
              #pragma unroll
              for (int reg=0; reg<4; ++reg)
                mybase[(4*q+reg)*MSR + 16*c2 + m] = packhl(Macc[ct][reg]);
            }
            uint32_t ua[8], ub[8];
            ld8(&mybase[m*MSR + 8*q], ua);
            FragHL fa = mkfrag(ua);
            ld8(&knN[m*KP + ((32*kk + 8*q) ^ swm)], ub);
            FragHL fb = mkfrag(ub);
            v0 = mfma16(fa.h, fb.h, v0);
            v0 = mfma16(fa.h, fb.l, v0);
            v0 = mfma16(fa.l, fb.h, v0);
            ld8(&knN[(16+m)*KP + ((32*kk + 8*q) ^ swm2)], ub);
            fb = mkfrag(ub);
            v1 = mfma16(fa.h, fb.h, v1);
            v1 = mfma16(fa.h, fb.l, v1);
            v1 = mfma16(fa.l, fb.h, v1);
          }
          // fold partial c(ch+1) = nrm*kn - vpP (corr subtracted in post)
          float* vpW = &vp0L[(1-sel)*VPW];
          const float nr0 = nrm_l[((ch+1)&3)*CC + m];
          const float nr1 = nrm_l[((ch+1)&3)*CC + 16 + m];
          const uint4 r0 = *reinterpret_cast<const uint4*>(&knN[m*KP + ((h0 + 4*q) ^ swm)]);
          const uint4 r1 = *reinterpret_cast<const uint4*>(&knN[(16+m)*KP + ((h0 + 4*q) ^ swm2)]);
          const uint32_t* pr0 = &r0.x; const uint32_t* pr1 = &r1.x;
          #pragma unroll
          for (int reg=0; reg<4; ++reg) {
            const int h = h0 + 4*q + reg;
            vpW[m*VS + h]      = nr0*unpackhl(pr0[reg]) - v0[reg];
            vpW[(16+m)*VS + h] = nr1*unpackhl(pr1[reg]) - v1[reg];
          }
        }
      }

      __syncthreads();                     // B2
      if (ch==NCH-1) break;

      // ---- post phase: corr + staging (kn DMA + knT reg-staged) ----
      {
        // knT source loads issued early (global, L2-hot), written after corr
        uint2 tv[4];
        #pragma unroll
        for (int r=0; r<4; ++r) {
          const int t = (wv-1)*4 + r;
          tv[r] = *reinterpret_cast<const uint2*>(
              &knb[(size_t)ch*CC*Hn + t*Hn + 2*lane]);
        }

        // fa = AD(ch)^T fragment from adT (2 b128); reused by E(ch+1)
        {
          const int rowA = h0 + m;
          const int swa = ((rowA>>3)&3)<<3;
          uint32_t ua[8];
          ld8(&adT[rowA*ADT + (8*q ^ swa)], ua);
          faAD = mkfrag(ua);
        }
        // corr = AD(ch)^T * Gcross  (B rows from GxT via float4)
        f32x4 c0 = (f32x4){0.f,0.f,0.f,0.f};
        f32x4 c1 = (f32x4){0.f,0.f,0.f,0.f};
        {
          const int swg = (m&3)<<3;
          uint32_t gbu[8];
          {
            const float4 ga = *reinterpret_cast<const float4*>(
                &GxT[m*GXS + (8*q ^ swg)]);
            const float4 gc = *reinterpret_cast<const float4*>(
                &GxT[m*GXS + (8*q ^ swg) + 4]);
            gbu[0]=packhl(ga.x); gbu[1]=packhl(ga.y);
            gbu[2]=packhl(ga.z); gbu[3]=packhl(ga.w);
            gbu[4]=packhl(gc.x); gbu[5]=packhl(gc.y);
            gbu[6]=packhl(gc.z); gbu[7]=packhl(gc.w);
          }
          FragHL fb = mkfrag(gbu);
          c0 = mfma16(faAD.h, fb.h, c0);
          c0 = mfma16(faAD.h, fb.l, c0);
          c0 = mfma16(faAD.l, fb.h, c0);
          {
            const float4 ga = *reinterpret_cast<const float4*>(
                &GxT[(16+m)*GXS + (8*q ^ swg)]);
            const float4 gc = *reinterpret_cast<const float4*>(
                &GxT[(16+m)*GXS + (8*q ^ swg) + 4]);
            gbu[0]=packhl(ga.x); gbu[1]=packhl(ga.y);
            gbu[2]=packhl(ga.z); gbu[3]=packhl(ga.w);
            gbu[4]=packhl(gc.x); gbu[5]=packhl(gc.y);
            gbu[6]=packhl(gc.z); gbu[7]=packhl(gc.w);
          }
          fb = mkfrag(gbu);
          c1 = mfma16(faAD.h, fb.h, c1);
          c1 = mfma16(faAD.h, fb.l, c1);
          c1 = mfma16(faAD.l, fb.h, c1);
        }
        // complete fold: vp0L[1-sel] -= corr
        {
          float* vpW = &vp0L[(1-sel)*VPW];
          #pragma unroll
          for (int reg=0; reg<4; ++reg) {
            const int h = h0 + 4*q + reg;
            vpW[m*VS + h]      -= c0[reg];
            vpW[(16+m)*VS + h] -= c1[reg];
          }
        }
        // knT(ch) transposed write: knT[h][t ^ swz(h)] = kn[t][h]
        {
          const int h2 = 2*lane;
          const int swz = ((h2>>3)&3)<<3;   // same for h2 and h2+1 (h2 even)
          #pragma unroll
          for (int r=0; r<4; ++r) {
            const int t = (wv-1)*4 + r;
            knT[h2*KTS     + (t ^ swz)] = tv[r].x;
            knT[(h2+1)*KTS + (t ^ swz)] = tv[r].y;
          }
        }
        // async kn staging: kn(ch+2) -> buf cur (pre-swizzled global src,
        // linear LDS dest). Drained by B1's implicit vmcnt(0).
        if (havn2) {
          const uint32_t* gsrc = knb + (size_t)(ch+2)*CC*Hn;
          uint32_t* ldst = &kn_p[cur*CC*KP];
          #pragma unroll
          for (int r=0; r<4; ++r) {
            const int t = (wv-1)*4 + r;
            const int sw = ((t>>3)&3)<<3;
            #pragma unroll
            for (int half=0; half<2; ++half) {
              gload_lds4(gsrc + t*Hn + ((half*64 + lane) ^ sw),
                         &ldst[t*KP + half*64]);
            }
          }
          if (tid >= 288 && tid < 320) nrm_l[((ch+2)&3)*CC + (tid-288)] = pfn;
        }
      }
      __syncthreads();                     // B1
    }
  } else if (wv <= 10) {
    // ========================= GxT loop =========================
    const int tj = wv - 9;
    #pragma unroll 1
    for (int ch=0; ch<NCH; ++ch) {
      const int cur = ch&1, nx1 = (ch+1)&1;
      const uint32_t* knc = &kn_p[cur*CC*KP];
      const uint32_t* knN = &kn_p[nx1*CC*KP];
      const bool havn = (ch+1 < NCH);

      if (havn) {
        #pragma unroll
        for (int ts=0; ts<2; ++ts) {
          const int ra = 16*tj+m, rb = 16*ts+m;
          const int swa = ((ra>>3)&3)<<3, swb = ((rb>>3)&3)<<3;
          f32x4 g4 = (f32x4){0.f,0.f,0.f,0.f};
          #pragma unroll
          for (int kk=0; kk<4; ++kk) {
            uint32_t ua[8], ub[8];
            ld8(&knN[ra*KP + ((32*kk + 8*q) ^ swa)], ua);
            ld8(&knc[rb*KP + ((32*kk + 8*q) ^ swb)], ub);
            FragHL fa = mkfrag(ua), fb = mkfrag(ub);
            g4 = mfma16(fa.h, fb.h, g4);
            g4 = mfma16(fa.h, fb.l, g4);
            g4 = mfma16(fa.l, fb.h, g4);
          }
          // write with per-row swizzle: col' = col ^ 8*(row&3), row&3 == reg
          #pragma unroll
          for (int reg=0; reg<4; ++reg)
            GxT[(16*tj + 4*q + reg)*GXS + ((16*ts + m) ^ (reg<<3))] = g4[reg];
        }
      }
      __syncthreads();                     // B2
      if (ch==NCH-1) break;
      __syncthreads();                     // B1
    }
  } else {
    // ========================= Gram loop =========================
    #pragma unroll 1
    for (int ch=0; ch<NCH; ++ch) {
      const int nx1 = (ch+1)&1;
      const int sel = ch & 1;
      const uint32_t* knN = &kn_p[nx1*CC*KP];
      const bool havn = (ch+1 < NCH);

      if (havn) {
        #pragma unroll
        for (int gi=0; gi<3; ++gi) {        // (0,0),(0,1)+T,(1,1)
          const int ti = (gi==2) ? 1 : 0;
          const int si = (gi==0) ? 0 : 1;
          const int ra = 16*ti+m, rb = 16*si+m;
          const int swa = ((ra>>3)&3)<<3, swb = ((rb>>3)&3)<<3;
          f32x4 g4 = (f32x4){0.f,0.f,0.f,0.f};
          #pragma unroll
          for (int kk=0; kk<4; ++kk) {
            uint32_t ua[8], ub[8];
            ld8(&knN[ra*KP + ((32*kk + 8*q) ^ swa)], ua);
            ld8(&knN[rb*KP + ((32*kk + 8*q) ^ swb)], ub);
            FragHL fa = mkfrag(ua), fb = mkfrag(ub);
            g4 = mfma16(fa.h, fb.h, g4);
            g4 = mfma16(fa.h, fb.l, g4);
            g4 = mfma16(fa.l, fb.h, g4);
          }
          float* GtW = &Gt[(1-sel)*CC*GS];
          #pragma unroll
          for (int reg=0; reg<4; ++reg)
            GtW[(16*ti + 4*q + reg)*GS + 16*si + m] = g4[reg];
          if (gi==1) {
            #pragma unroll
            for (int reg=0; reg<4; ++reg)
              GtW[(16*si + m)*GS + 16*ti + 4*q + reg] = g4[reg];
          }
        }
      }
      __syncthreads();                     // B2
      if (ch==NCH-1) break;
      __syncthreads();                     // B1
    }
  }
}

// ---------------------------------------------------------------------------
// Phase 3a: o1 = read @ rp_w^T + rp_b
// ---------------------------------------------------------------------------
__global__ __launch_bounds__(128) void p3a(
    const float* __restrict__ read_ws, const float* __restrict__ rp_w,
    const float* __restrict__ rp_b, float* __restrict__ o1_ws)
{
  __shared__ float rd[128];
  const int b = blockIdx.x, t = threadIdx.x;
  rd[t] = read_ws[b*Hn + t];
  __syncthreads();
  float acc = rp_b[t];
  const float* wr = rp_w + t*Hn;
  #pragma unroll 4
  for (int i = 0; i < Hn; ++i) acc += rd[i]*wr[i];
  o1_ws[b*Hn + t] = acc;
}

// ---------------------------------------------------------------------------
// Phase 3b: out = o1 @ out_w^T + out_b
// ---------------------------------------------------------------------------
__global__ __launch_bounds__(256) void p3b(
    const float* __restrict__ o1_ws, const float* __restrict__ out_w,
    const float* __restrict__ out_b, float* __restrict__ out)
{
  __shared__ __align__(16) float o1[8192];       // [64][128]
  const int tid = threadIdx.x;
  #pragma unroll
  for (int c = 0; c < 32; ++c) o1[c*256+tid] = o1_ws[c*256+tid];
  __syncthreads();
  const int v = blockIdx.x*256 + tid;            // 125*256 == 32000
  float acc[64];
  const float ob = out_b[v];
  #pragma unroll
  for (int bb = 0; bb < 64; ++bb) acc[bb] = ob;
  const float4* wrow = reinterpret_cast<const float4*>(out_w + (size_t)v*Hn);
  #pragma unroll 1
  for (int r4 = 0; r4 < 32; ++r4) {
    const float4 wv = wrow[r4];
    #pragma unroll
    for (int bb = 0; bb < 64; ++bb) {
      const float4 ov = *reinterpret_cast<const float4*>(&o1[bb*Hn + r4*4]);
      acc[bb] += wv.x*ov.x + wv.y*ov.y + wv.z*ov.z + wv.w*ov.w;
    }
  }
  #pragma unroll
  for (int bb = 0; bb < 64; ++bb) out[(size_t)bb*Vn + v] = acc[bb];
}

// ---------------------------------------------------------------------------
extern "C" void kernel_launch(void* const* d_in, const int* in_sizes, int n_in,
                              void* d_out, int out_size, void* d_ws, size_t ws_size,
                              hipStream_t stream)
{
  const int*   seq     = (const int*)  d_in[0];
  const float* embed_w = (const float*)d_in[1];
  const float* ff_w1   = (const float*)d_in[2];
  const float* ff_b1   = (const float*)d_in[3];
  const float* ff_w2   = (const float*)d_in[4];
  const float* ff_b2   = (const float*)d_in[5];
  const float* ln_g    = (const float*)d_in[6];
  const float* ln_b    = (const float*)d_in[7];
  const float* kp_w    = (const float*)d_in[8];
  const float* rp_w    = (const float*)d_in[9];
  const float* rp_b    = (const float*)d_in[10];
  const float* out_w   = (const float*)d_in[11];
  const float* out_b   = (const float*)d_in[12];

  float* ws          = (float*)d_ws;
  uint32_t* knp_all  = (uint32_t*)ws;                 // B*L*H u32 (packed hi/lo)
  float* norm_all    = ws + (size_t)Bn*Ln*Hn;         // B*L
  float* read_ws     = norm_all + (size_t)Bn*Ln;      // B*H
  float* o1_ws       = read_ws + Bn*Hn;               // B*H
  uint32_t* wp       = (uint32_t*)(o1_ws + Bn*Hn);    // 81920 u32 packed weights

  p0_pack<<<dim3(160), dim3(256), 0, stream>>>(ff_w1, ff_w2, kp_w, wp);
  p1_fused<<<dim3(2048), dim3(256), 0, stream>>>(
      seq, embed_w, wp, ff_b1, ff_b2, ln_g, ln_b, knp_all, norm_all);
  p2_scan<<<dim3(64), dim3(768), 0, stream>>>(knp_all, norm_all, read_ws);
  p3a<<<dim3(64), dim3(128), 0, stream>>>(read_ws, rp_w, rp_b, o1_ws);
  p3b<<<dim3(125), dim3(256), 0, stream>>>(o1_ws, out_w, out_b, (float*)d_out);
}

// Round 12
// 695.006 us; speedup vs baseline: 1.0357x; 1.0357x over previous
//
#include <hip/hip_runtime.h>
#include <hip/hip_bf16.h>
#include <stdint.h>

#define Bn 64
#define Ln 2048
#define Hn 128
#define Vn 32000
#define THn 256            // 2*H
#define LAMBDA_ (1.0f/2048.0f)
#define CC 32              // scan chunk size
#define NCH (Ln/CC)        // 64 chunks
#define KP  132            // p2 kn_p row stride (uints)
#define KTS 36             // p2 knT row stride (uints)
#define VS  132            // p2 vp0L row stride (floats)
#define VPW (CC*VS)        // p2 vp0L buffer size
#define ADS 131            // p2 adL row stride (floats)
#define ADW (CC*ADS+4)     // p2 adL buffer size (floats)
#define GS  36             // p2 Gt row stride
#define GXS 36             // p2 GxT row stride (floats, swizzled vector access)
#define MSR 36             // p2 m_scratch row stride (uints)
#define MSW 576            // p2 m_scratch per-wave size (16*36)
#define HS  132            // p1 h_p/u_p row stride (uints)

typedef short bf16x8 __attribute__((ext_vector_type(8)));
typedef float f32x4  __attribute__((ext_vector_type(4)));

__device__ __forceinline__ float rdlane(float v, int s) {
  return __int_as_float(__builtin_amdgcn_readlane(__float_as_int(v), s));
}

// DPP-based add step: x += dpp_select(x). ctrl is a template param (must be
// an ICE at the builtin call site).
template <int CTRL>
__device__ __forceinline__ float dpp_add(float x) {
  int t = __builtin_amdgcn_update_dpp(0, __float_as_int(x), CTRL, 0xf, 0xf, false);
  return x + __int_as_float(t);
}
// full 64-lane sum, result broadcast via readlane(63)
__device__ __forceinline__ float wave_sum64(float x) {
  x = dpp_add<0x111>(x);   // row_shr:1
  x = dpp_add<0x112>(x);   // row_shr:2
  x = dpp_add<0x114>(x);   // row_shr:4
  x = dpp_add<0x118>(x);   // row_shr:8  -> lane 15 of each row = row sum
  x = dpp_add<0x142>(x);   // row_bcast:15
  x = dpp_add<0x143>(x);   // row_bcast:31 -> lane63 = total
  return rdlane(x, 63);
}

// pack fp32 -> (bf16 hi in low16, bf16 lo in high16), truncation split
__device__ __forceinline__ uint32_t packhl(float x) {
  uint32_t bx = __float_as_uint(x);
  float hf = __uint_as_float(bx & 0xFFFF0000u);
  uint32_t bl = __float_as_uint(x - hf);
  return (bx >> 16) | (bl & 0xFFFF0000u);
}
__device__ __forceinline__ float unpackhl(uint32_t u) {
  return __uint_as_float(u << 16) + __uint_as_float(u & 0xFFFF0000u);
}

struct FragHL { bf16x8 h; bf16x8 l; };
__device__ __forceinline__ FragHL mkfrag(const uint32_t* u) {
  union { uint32_t a[4]; bf16x8 v; } H, L;
  H.a[0] = __builtin_amdgcn_perm(u[1], u[0], 0x05040100u);
  H.a[1] = __builtin_amdgcn_perm(u[3], u[2], 0x05040100u);
  H.a[2] = __builtin_amdgcn_perm(u[5], u[4], 0x05040100u);
  H.a[3] = __builtin_amdgcn_perm(u[7], u[6], 0x05040100u);
  L.a[0] = __builtin_amdgcn_perm(u[1], u[0], 0x07060302u);
  L.a[1] = __builtin_amdgcn_perm(u[3], u[2], 0x07060302u);
  L.a[2] = __builtin_amdgcn_perm(u[5], u[4], 0x07060302u);
  L.a[3] = __builtin_amdgcn_perm(u[7], u[6], 0x07060302u);
  FragHL f; f.h = H.v; f.l = L.v; return f;
}

__device__ __forceinline__ void ld8(const uint32_t* p, uint32_t* u) {
  const uint4 a = *reinterpret_cast<const uint4*>(p);
  const uint4 b = *reinterpret_cast<const uint4*>(p + 4);
  u[0]=a.x; u[1]=a.y; u[2]=a.z; u[3]=a.w;
  u[4]=b.x; u[5]=b.y; u[6]=b.z; u[7]=b.w;
}

__device__ __forceinline__ bf16x8 asbf(uint4 u) {
  union { uint4 a; bf16x8 v; } c; c.a = u; return c.v;
}

__device__ __forceinline__ f32x4 mfma16(bf16x8 a, bf16x8 b, f32x4 c) {
  return __builtin_amdgcn_mfma_f32_16x16x32_bf16(a, b, c, 0, 0, 0);
}

// async global->LDS, width 4 bytes, per-lane global addr, wave-uniform LDS base
__device__ __forceinline__ void gload_lds4(const uint32_t* g, uint32_t* l) {
  __builtin_amdgcn_global_load_lds(
      (const __attribute__((address_space(1))) void*)g,
      (__attribute__((address_space(3))) void*)l, 4, 0, 0);
}

// ---------------------------------------------------------------------------
// p0: pack weights once into fragment-ready hi/lo bf16-pair arrays in ws.
// ---------------------------------------------------------------------------
__global__ __launch_bounds__(256) void p0_pack(
    const float* __restrict__ w1, const float* __restrict__ w2,
    const float* __restrict__ kp, uint32_t* __restrict__ wp)
{
  const int id = blockIdx.x*256 + threadIdx.x;   // pair index, 0..40959
  const float* src; uint32_t *dh, *dl; int p;
  if (id < 16384)      { src = w1; p = id;         dh = wp;         dl = wp+16384; }
  else if (id < 32768) { src = w2; p = id-16384;   dh = wp+32768;   dl = wp+49152; }
  else                 { src = kp; p = id-32768;   dh = wp+65536;   dl = wp+73728; }
  const float x0 = src[2*p], x1 = src[2*p+1];
  const uint32_t b0 = __float_as_uint(x0), b1 = __float_as_uint(x1);
  const float l0f = x0 - __uint_as_float(b0 & 0xFFFF0000u);
  const float l1f = x1 - __uint_as_float(b1 & 0xFFFF0000u);
  dh[p] = (b0 >> 16) | ((b1 >> 16) << 16);
  dl[p] = (__float_as_uint(l0f) >> 16) | ((__float_as_uint(l1f) >> 16) << 16);
}

// ---------------------------------------------------------------------------
// Phase 1 (MFMA, unchanged)
// ---------------------------------------------------------------------------
__global__ __launch_bounds__(256, 2) void p1_fused(
    const int* __restrict__ seq,
    const float* __restrict__ embed_w,
    const uint32_t* __restrict__ wp,
    const float* __restrict__ ff_b1, const float* __restrict__ ff_b2,
    const float* __restrict__ ln_g, const float* __restrict__ ln_b,
    uint32_t* __restrict__ knp_all, float* __restrict__ norm_all)
{
  __shared__ __align__(16) uint32_t h_p[64*HS];   // packed h, later packed hn
  __shared__ __align__(16) uint32_t u_p[64*HS];   // packed u (one 128-col half)
  __shared__ float part1[256], part2[256];
  __shared__ float mul[64], rsl[64];
  __shared__ int sid[64];

  const int tid  = threadIdx.x;
  const int lane = tid & 63;
  const int w    = __builtin_amdgcn_readfirstlane(tid >> 6);
  const int q4   = lane >> 4;
  const int m16  = lane & 15;
  const int tile0 = blockIdx.x * 64;

  const uint32_t* w1h = wp;
  const uint32_t* w1l = wp + 16384;
  const uint32_t* w2h = wp + 32768;
  const uint32_t* w2l = wp + 49152;
  const uint32_t* kph = wp + 65536;
  const uint32_t* kpl = wp + 73728;

  if (tid < 64) sid[tid] = seq[tile0 + tid];
  __syncthreads();

  { // embed gather -> packed h_p[token][feature]
    const int t = tid >> 2, part = tid & 3;
    const float4* erow =
        reinterpret_cast<const float4*>(embed_w + (size_t)sid[t]*Hn) + part*8;
    #pragma unroll
    for (int c = 0; c < 8; ++c) {
      float4 v = erow[c];
      int j = part*32 + c*4;
      h_p[t*HS+j+0] = packhl(v.x); h_p[t*HS+j+1] = packhl(v.y);
      h_p[t*HS+j+2] = packhl(v.z); h_p[t*HS+j+3] = packhl(v.w);
    }
  }
  __syncthreads();

  f32x4 acc2[4][2];
  #pragma unroll
  for (int tt=0;tt<4;++tt)
    #pragma unroll
    for (int ct=0;ct<2;++ct) acc2[tt][ct] = (f32x4){0.f,0.f,0.f,0.f};

  #pragma unroll 1
  for (int ho=0; ho<2; ++ho) {
    #pragma unroll 1
    for (int tt=0; tt<4; ++tt) {
      FragHL fa[4];
      #pragma unroll
      for (int kk=0;kk<4;++kk) {
        uint32_t ua[8];
        ld8(&h_p[(16*tt+m16)*HS + 32*kk + 8*q4], ua);
        fa[kk] = mkfrag(ua);
      }
      #pragma unroll
      for (int ct=0; ct<2; ++ct) {
        const int ob = 128*ho + 32*w + 16*ct;
        f32x4 a = (f32x4){0.f,0.f,0.f,0.f};
        #pragma unroll
        for (int kk=0;kk<4;++kk) {
          const size_t wi = (size_t)(ob+m16)*64 + 16*kk + 4*q4;
          bf16x8 bh = asbf(*reinterpret_cast<const uint4*>(&w1h[wi]));
          bf16x8 bl = asbf(*reinterpret_cast<const uint4*>(&w1l[wi]));
          a = mfma16(fa[kk].h, bh, a);
          a = mfma16(fa[kk].h, bl, a);
          a = mfma16(fa[kk].l, bh, a);
        }
        const float bb = ff_b1[ob + m16];
        #pragma unroll
        for (int reg=0;reg<4;++reg) {
          float uv = fmaxf(a[reg] + bb, 0.f);
          u_p[(16*tt+4*q4+reg)*HS + 32*w + 16*ct + m16] = packhl(uv);
        }
      }
    }
    __syncthreads();
    #pragma unroll 1
    for (int tt=0; tt<4; ++tt) {
      FragHL fu[4];
      #pragma unroll
      for (int kk=0;kk<4;++kk) {
        uint32_t ua[8];
        ld8(&u_p[(16*tt+m16)*HS + 32*kk + 8*q4], ua);
        fu[kk] = mkfrag(ua);
      }
      #pragma unroll
      for (int ct=0; ct<2; ++ct) {
        const int ib = 32*w + 16*ct;
        f32x4 a = acc2[tt][ct];
        #pragma unroll
        for (int kk=0;kk<4;++kk) {
          const size_t wi = (size_t)(ib+m16)*128 + 64*ho + 16*kk + 4*q4;
          bf16x8 bh = asbf(*reinterpret_cast<const uint4*>(&w2h[wi]));
          bf16x8 bl = asbf(*reinterpret_cast<const uint4*>(&w2l[wi]));
          a = mfma16(fu[kk].h, bh, a);
          a = mfma16(fu[kk].h, bl, a);
          a = mfma16(fu[kk].l, bh, a);
        }
        acc2[tt][ct] = a;
      }
    }
    __syncthreads();
  }

  // ---- bias + residual; LN partials ----
  float xx[4][2][4];
  #pragma unroll
  for (int tt=0;tt<4;++tt)
    #pragma unroll
    for (int ct=0;ct<2;++ct) {
      const int col = 32*w + 16*ct + m16;
      const float b2 = ff_b2[col];
      #pragma unroll
      for (int reg=0;reg<4;++reg) {
        const float hval = unpackhl(h_p[(16*tt+4*q4+reg)*HS + col]);
        xx[tt][ct][reg] = acc2[tt][ct][reg] + b2 + hval;
      }
    }
  #pragma unroll
  for (int tt=0;tt<4;++tt)
    #pragma unroll
    for (int reg=0;reg<4;++reg) {
      float s1 = xx[tt][0][reg] + xx[tt][1][reg];
      float s2 = xx[tt][0][reg]*xx[tt][0][reg] + xx[tt][1][reg]*xx[tt][1][reg];
      s1 += __shfl_xor(s1,1); s1 += __shfl_xor(s1,2);
      s1 += __shfl_xor(s1,4); s1 += __shfl_xor(s1,8);
      s2 += __shfl_xor(s2,1); s2 += __shfl_xor(s2,2);
      s2 += __shfl_xor(s2,4); s2 += __shfl_xor(s2,8);
      if (m16==0) {
        part1[w*64 + 16*tt+4*q4+reg] = s1;
        part2[w*64 + 16*tt+4*q4+reg] = s2;
      }
    }
  __syncthreads();
  if (tid < 64) {
    const float mu = (part1[tid]+part1[64+tid]+part1[128+tid]+part1[192+tid])*(1.0f/128.0f);
    const float ms = (part2[tid]+part2[64+tid]+part2[128+tid]+part2[192+tid])*(1.0f/128.0f);
    mul[tid] = mu;
    rsl[tid] = rsqrtf(ms - mu*mu + 1e-5f);
  }
  __syncthreads();

  #pragma unroll
  for (int tt=0;tt<4;++tt)
    #pragma unroll
    for (int ct=0;ct<2;++ct) {
      const int col = 32*w + 16*ct + m16;
      const float g = ln_g[col], bb = ln_b[col];
      #pragma unroll
      for (int reg=0;reg<4;++reg) {
        const int tok = 16*tt+4*q4+reg;
        const float hn = (xx[tt][ct][reg] - mul[tok])*rsl[tok]*g + bb;
        h_p[tok*HS + col] = packhl(hn);
      }
    }
  __syncthreads();

  // ---- k projection ----
  f32x4 ak[4][2];
  #pragma unroll 1
  for (int tt=0;tt<4;++tt) {
    FragHL fh[4];
    #pragma unroll
    for (int kk=0;kk<4;++kk) {
      uint32_t ua[8];
      ld8(&h_p[(16*tt+m16)*HS + 32*kk + 8*q4], ua);
      fh[kk] = mkfrag(ua);
    }
    #pragma unroll
    for (int ct=0;ct<2;++ct) {
      const int ob = 32*w + 16*ct;
      f32x4 a = (f32x4){0.f,0.f,0.f,0.f};
      #pragma unroll
      for (int kk=0;kk<4;++kk) {
        const size_t wi = (size_t)(ob+m16)*64 + 16*kk + 4*q4;
        bf16x8 bh = asbf(*reinterpret_cast<const uint4*>(&kph[wi]));
        bf16x8 bl = asbf(*reinterpret_cast<const uint4*>(&kpl[wi]));
        a = mfma16(fh[kk].h, bh, a);
        a = mfma16(fh[kk].h, bl, a);
        a = mfma16(fh[kk].l, bh, a);
      }
      ak[tt][ct] = a;
    }
  }
  #pragma unroll
  for (int tt=0;tt<4;++tt)
    #pragma unroll
    for (int reg=0;reg<4;++reg) {
      float s = ak[tt][0][reg]*ak[tt][0][reg] + ak[tt][1][reg]*ak[tt][1][reg];
      s += __shfl_xor(s,1); s += __shfl_xor(s,2);
      s += __shfl_xor(s,4); s += __shfl_xor(s,8);
      if (m16==0) part1[w*64 + 16*tt+4*q4+reg] = s;
    }
  __syncthreads();
  if (tid < 64) {
    const float nn = part1[tid]+part1[64+tid]+part1[128+tid]+part1[192+tid];
    const float nrm = sqrtf(nn);
    norm_all[tile0 + tid] = nrm;
    mul[tid] = 1.0f / fmaxf(nrm, 1e-12f);
  }
  __syncthreads();
  #pragma unroll
  for (int tt=0;tt<4;++tt)
    #pragma unroll
    for (int ct=0;ct<2;++ct) {
      const int col = 32*w + 16*ct + m16;
      #pragma unroll
      for (int reg=0;reg<4;++reg) {
        const int tok = 16*tt+4*q4+reg;
        knp_all[(size_t)(tile0+tok)*Hn + col] = packhl(ak[tt][ct][reg]*mul[tok]);
      }
    }
}

// ---------------------------------------------------------------------------
// Phase 2 (r20): r18 base + carried faAD + vectorized GxT B-side.
//   r19 post-mortem: moving the AD transpose onto wave0's serial path was
//   an 8-way-conflict store + packhl on the critical path (-23us). r20
//   reverts wave0 to r18's conflict-free raw-float adL writes and keeps
//   only the off-path wins:
//   - corr(ch) builds the AD^T fragment (msc roundtrip, as r18) and CARRIES
//     it in regs (faAD) for E(ch+1): E loses 8 b32 reads + 8 packhl/wave.
//   - GxT stride 36 + per-row XOR swizzle (col ^ 8*(row&3)): corr's B rows
//     read as 8 b128 (was 32 scalar b32).
// ---------------------------------------------------------------------------
__global__ __launch_bounds__(768, 3) void p2_scan(
    const uint32_t* __restrict__ knp_all, const float* __restrict__ norm_all,
    float* __restrict__ read_ws)
{
  const int tid  = threadIdx.x;
  const int lane = tid & 63;
  const int wv   = __builtin_amdgcn_readfirstlane(tid >> 6);  // 0..11
  const int q    = lane >> 4;
  const int m    = lane & 15;
  const int b    = blockIdx.x;

  __shared__ __align__(16) uint32_t kn_p[2*CC*KP];  // double-buffered, swizzled
  __shared__ __align__(16) uint32_t knT [128*KTS];  // transposed copy for E
  __shared__ __align__(16) float    vp0L[2*VPW];    // double-buffered c values
  __shared__ __align__(16) float    adL [2*ADW];    // double-buffered
  __shared__ __align__(16) float    Gt  [2*CC*GS];  // double-buffered Gram
  __shared__ __align__(16) float    GxT [CC*GXS];   // GxT[j][s^8*(j&3)]
  __shared__ __align__(16) uint32_t msc [8*MSW];    // transpose scratch
  __shared__ float nrm_l[4*CC];

  const uint32_t* knb = knp_all + (size_t)b*Ln*Hn;
  const float*    nb  = norm_all + (size_t)b*Ln;

  const int swm  = ((m>>3)&3)<<3;         // swizzle for row m (m<16)
  const int swm2 = (((16+m)>>3)&3)<<3;    // swizzle for row 16+m

  { // prologue stage: kn(0)->buf0, kn(1)->buf1 (swizzled), nrm slots 0,1
    if (tid < 256) {
      const int t = tid>>3, g = tid&7;
      const int sw = ((t>>3)&3)<<3;
      const uint4* src = reinterpret_cast<const uint4*>(knb + t*Hn + g*16);
      uint32_t* dstb = &kn_p[t*KP];
      *reinterpret_cast<uint4*>(&dstb[(16*g+0) ^ sw])  = src[0];
      *reinterpret_cast<uint4*>(&dstb[(16*g+4) ^ sw])  = src[1];
      *reinterpret_cast<uint4*>(&dstb[(16*g+8) ^ sw])  = src[2];
      *reinterpret_cast<uint4*>(&dstb[(16*g+12) ^ sw]) = src[3];
    } else if (tid < 512) {
      const int idx = tid-256, t = idx>>3, g = idx&7;
      const int sw = ((t>>3)&3)<<3;
      const uint4* src = reinterpret_cast<const uint4*>(knb + CC*Hn + t*Hn + g*16);
      uint32_t* dstb = &kn_p[CC*KP + t*KP];
      *reinterpret_cast<uint4*>(&dstb[(16*g+0) ^ sw])  = src[0];
      *reinterpret_cast<uint4*>(&dstb[(16*g+4) ^ sw])  = src[1];
      *reinterpret_cast<uint4*>(&dstb[(16*g+8) ^ sw])  = src[2];
      *reinterpret_cast<uint4*>(&dstb[(16*g+12) ^ sw]) = src[3];
    } else if (tid < 512+2*CC) {
      nrm_l[tid-512] = nb[tid-512];
    }
  }
  __syncthreads();

  { // prologue compute: Gram(0) -> Gt[0] (waves 9-11); c(0) (waves 1-8)
    if (wv >= 9) {
      const int gi = wv - 9;                  // 0,1,2 -> (0,0),(0,1)+T,(1,1)
      if (gi < 3) {
        const int ti = (gi==2) ? 1 : 0;
        const int si = (gi==0) ? 0 : 1;
        const int ra = 16*ti+m, rb = 16*si+m;
        const int swa = ((ra>>3)&3)<<3, swb = ((rb>>3)&3)<<3;
        f32x4 g4 = (f32x4){0.f,0.f,0.f,0.f};
        #pragma unroll
        for (int kk=0; kk<4; ++kk) {
          uint32_t ua[8], ub[8];
          ld8(&kn_p[ra*KP + ((32*kk + 8*q) ^ swa)], ua);
          ld8(&kn_p[rb*KP + ((32*kk + 8*q) ^ swb)], ub);
          FragHL fa = mkfrag(ua), fb = mkfrag(ub);
          g4 = mfma16(fa.h, fb.h, g4);
          g4 = mfma16(fa.h, fb.l, g4);
          g4 = mfma16(fa.l, fb.h, g4);
        }
        #pragma unroll
        for (int reg=0; reg<4; ++reg)
          Gt[(16*ti + 4*q + reg)*GS + 16*si + m] = g4[reg];
        if (gi==1) {
          #pragma unroll
          for (int reg=0; reg<4; ++reg)
            Gt[(16*si + m)*GS + 16*ti + 4*q + reg] = g4[reg];
        }
      }
    }
    if (wv >= 1 && wv <= 8) {
      const int h0 = 16*(wv-1);
      const float nr0 = nrm_l[m], nr1 = nrm_l[16+m];
      const uint4 r0 = *reinterpret_cast<const uint4*>(&kn_p[m*KP + ((h0 + 4*q) ^ swm)]);
      const uint4 r1 = *reinterpret_cast<const uint4*>(&kn_p[(16+m)*KP + ((h0 + 4*q) ^ swm2)]);
      const uint32_t* pr0 = &r0.x; const uint32_t* pr1 = &r1.x;
      #pragma unroll
      for (int reg=0; reg<4; ++reg) {
        const int h = h0 + 4*q + reg;
        vp0L[m*VS + h]      = nr0*unpackhl(pr0[reg]);
        vp0L[(16+m)*VS + h] = nr1*unpackhl(pr1[reg]);
      }
    }
  }
  __syncthreads();

  if (wv == 0) {
    // ======================= serial-scan loop (r18 form) =====================
    #pragma unroll 1
    for (int ch=0; ch<NCH; ++ch) {
      const int cur = ch&1;
      const int sel = ch & 1;
      const uint32_t* knc = &kn_p[cur*CC*KP];

      float ad0[CC], ad1[CC];
      float* adW = &adL[sel*ADW];
      const float* vpR = &vp0L[sel*VPW];
      const float* GtS = &Gt[sel*CC*GS];
      const int lid = lane & 31;
      const float nrmv = nrm_l[(ch&3)*CC + lid];
      float grt = GtS[0*GS + lid];            // 2-deep gr pipeline (3 regs)
      float grn = GtS[1*GS + lid];
      __builtin_amdgcn_s_setprio(1);
      #pragma unroll
      for (int t=0;t<CC;++t) {
        float grn2 = 0.f;
        if (t+2 < CC) grn2 = GtS[(t+2)*GS + lid];
        float a0c0 = vpR[t*VS + lane];        // c0
        float a1c0 = vpR[t*VS + 64 + lane];   // c1
        float a0c1=0.f, a0c2=0.f, a0c3=0.f;
        float a1c1=0.f, a1c2=0.f, a1c3=0.f;
        #pragma unroll
        for (int s=0; s<t; ++s) {                   // static: only s<t emitted
          const float g = rdlane(grt, s);
          switch (s & 3) {
            case 0: a0c0 -= g*ad0[s]; a1c0 -= g*ad1[s]; break;
            case 1: a0c1 -= g*ad0[s]; a1c1 -= g*ad1[s]; break;
            case 2: a0c2 -= g*ad0[s]; a1c2 -= g*ad1[s]; break;
            default:a0c3 -= g*ad0[s]; a1c3 -= g*ad1[s]; break;
          }
        }
        const float acc0 = (a0c0+a0c1)+(a0c2+a0c3);
        const float acc1 = (a1c0+a1c1)+(a1c2+a1c3);
        const float sqt = wave_sum64(acc0*acc0 + acc1*acc1);
        const float nrm = rdlane(nrmv, t);
        if (ch==NCH-1 && t==CC-1) {
          // read = M@q, q = nrm*kn; M.kn = nrm*kn - d
          const int swt = ((t>>3)&3)<<3;
          const float kn0 = unpackhl(knc[t*KP + (lane ^ swt)]);
          const float kn1 = unpackhl(knc[t*KP + ((64+lane) ^ swt)]);
          read_ws[b*Hn + lane]      = nrm*(nrm*kn0 - acc0);
          read_ws[b*Hn + 64 + lane] = nrm*(nrm*kn1 - acc1);
        } else {
          // gate: sqrt(sq) >= 0.4*nrm  <=>  sq >= 0.16*nrm*nrm (uniform)
          const float at = (sqt >= 0.16f*nrm*nrm) ? LAMBDA_ : 0.f;
          ad0[t] = at*acc0; ad1[t] = at*acc1;
          adW[t*ADS + lane]      = ad0[t];
          adW[t*ADS + 64 + lane] = ad1[t];
        }
        grt = grn; grn = grn2;
      }
      __builtin_amdgcn_s_setprio(0);

      __syncthreads();                     // B2
      if (ch==NCH-1) break;
      __syncthreads();                     // B1
    }
  } else if (wv <= 8) {
    // ================= E / vpP / fold / corr / staging =================
    f32x4 Macc[8];
    #pragma unroll
    for (int ct=0; ct<8; ++ct) Macc[ct] = (f32x4){0.f,0.f,0.f,0.f};
    const int h0 = 16*(wv-1);
    FragHL faAD;                           // AD^T fragment carried corr->E
    { uint32_t z[8] = {0,0,0,0,0,0,0,0}; faAD = mkfrag(z); }

    #pragma unroll 1
    for (int ch=0; ch<NCH; ++ch) {
      const int cur = ch&1, nx1 = (ch+1)&1;
      const int sel = ch & 1;
      const uint32_t* knN = &kn_p[nx1*CC*KP];
      const bool havn  = (ch+1 < NCH);
      const bool havn2 = (ch+2 < NCH);

      // nrm prefetch for ch+2 (1 VGPR, wave 4 hi-lanes only)
      float pfn = 0.f;
      if (havn2 && tid >= 288 && tid < 320) pfn = nb[(ch+2)*CC + (tid-288)];

      if (havn) {
        // ---- deferred E(ch-1): Macc += AD(ch-1)^T * Kn_{ch-1} ----
        // A-fragment carried in regs from corr(ch-1); B from knT.
        if (ch >= 1) {
          #pragma unroll
          for (int ct=0; ct<8; ++ct) {
            const int hcol = 16*ct + m;
            const int swz = ((hcol>>3)&3)<<3;
            uint32_t bu[8];
            ld8(&knT[hcol*KTS + (8*q ^ swz)], bu);
            FragHL fb = mkfrag(bu);
            Macc[ct] = mfma16(faAD.h, fb.h, Macc[ct]);
            Macc[ct] = mfma16(faAD.h, fb.l, Macc[ct]);
            Macc[ct] = mfma16(faAD.l, fb.h, Macc[ct]);
          }
        }
        // ---- vpP slice: v = M^{(ch)} * Kn_{ch+1}^T; fold into vp0L[1-sel] ----
        {
          f32x4 v0 = (f32x4){0.f,0.f,0.f,0.f};
          f32x4 v1 = (f32x4){0.f,0.f,0.f,0.f};
          uint32_t* mybase = &msc[(wv-1)*MSW];
          #pragma unroll
          for (int kk=0; kk<4; ++kk) {
            #pragma unroll
            for (int c2=0; c2<2; ++c2) {
              const int ct = 2*kk + c2;
              #pragma unroll
              for (int reg=0; reg<4; ++reg)
                mybase[(4*q+reg)*MSR + 16*c2 + m] = packhl(Macc[ct][reg]);
            }
            uint32_t ua[8], ub[8];
            ld8(&mybase[m*MSR + 8*q], ua);
            FragHL fa = mkfrag(ua);
            ld8(&knN[m*KP + ((32*kk + 8*q) ^ swm)], ub);
            FragHL fb = mkfrag(ub);
            v0 = mfma16(fa.h, fb.h, v0);
            v0 = mfma16(fa.h, fb.l, v0);
            v0 = mfma16(fa.l, fb.h, v0);
            ld8(&knN[(16+m)*KP + ((32*kk + 8*q) ^ swm2)], ub);
            fb = mkfrag(ub);
            v1 = mfma16(fa.h, fb.h, v1);
            v1 = mfma16(fa.h, fb.l, v1);
            v1 = mfma16(fa.l, fb.h, v1);
          }
          // fold partial c(ch+1) = nrm*kn - vpP (corr subtracted in post)
          float* vpW = &vp0L[(1-sel)*VPW];
          const float nr0 = nrm_l[((ch+1)&3)*CC + m];
          const float nr1 = nrm_l[((ch+1)&3)*CC + 16 + m];
          const uint4 r0 = *reinterpret_cast<const uint4*>(&knN[m*KP + ((h0 + 4*q) ^ swm)]);
          const uint4 r1 = *reinterpret_cast<const uint4*>(&knN[(16+m)*KP + ((h0 + 4*q) ^ swm2)]);
          const uint32_t* pr0 = &r0.x; const uint32_t* pr1 = &r1.x;
          #pragma unroll
          for (int reg=0; reg<4; ++reg) {
            const int h = h0 + 4*q + reg;
            vpW[m*VS + h]      = nr0*unpackhl(pr0[reg]) - v0[reg];
            vpW[(16+m)*VS + h] = nr1*unpackhl(pr1[reg]) - v1[reg];
          }
        }
      }

      __syncthreads();                     // B2
      if (ch==NCH-1) break;

      // ---- post phase: corr + staging (kn DMA + knT reg-staged) ----
      {
        // knT source loads issued early (global, L2-hot), written after corr
        uint2 tv[4];
        #pragma unroll
        for (int r=0; r<4; ++r) {
          const int t = (wv-1)*4 + r;
          tv[r] = *reinterpret_cast<const uint2*>(
              &knb[(size_t)ch*CC*Hn + t*Hn + 2*lane]);
        }

        // faAD = AD(ch)^T fragment via msc roundtrip (r18 form); kept for E
        {
          const float* adR = &adL[sel*ADW];
          uint32_t* mybase = &msc[(wv-1)*MSW];
          #pragma unroll
          for (int c2=0; c2<2; ++c2)
            #pragma unroll
            for (int reg=0; reg<4; ++reg)
              mybase[(4*q+reg)*MSR + 16*c2 + m] =
                  packhl(adR[(16*c2+m)*ADS + h0 + 4*q + reg]);
          uint32_t ua[8];
          ld8(&mybase[m*MSR + 8*q], ua);
          faAD = mkfrag(ua);
        }
        // corr = AD(ch)^T * Gcross  (B rows from GxT via float4)
        f32x4 c0 = (f32x4){0.f,0.f,0.f,0.f};
        f32x4 c1 = (f32x4){0.f,0.f,0.f,0.f};
        {
          const int swg = (m&3)<<3;
          uint32_t gbu[8];
          {
            const float4 ga = *reinterpret_cast<const float4*>(
                &GxT[m*GXS + (8*q ^ swg)]);
            const float4 gc = *reinterpret_cast<const float4*>(
                &GxT[m*GXS + (8*q ^ swg) + 4]);
            gbu[0]=packhl(ga.x); gbu[1]=packhl(ga.y);
            gbu[2]=packhl(ga.z); gbu[3]=packhl(ga.w);
            gbu[4]=packhl(gc.x); gbu[5]=packhl(gc.y);
            gbu[6]=packhl(gc.z); gbu[7]=packhl(gc.w);
          }
          FragHL fb = mkfrag(gbu);
          c0 = mfma16(faAD.h, fb.h, c0);
          c0 = mfma16(faAD.h, fb.l, c0);
          c0 = mfma16(faAD.l, fb.h, c0);
          {
            const float4 ga = *reinterpret_cast<const float4*>(
                &GxT[(16+m)*GXS + (8*q ^ swg)]);
            const float4 gc = *reinterpret_cast<const float4*>(
                &GxT[(16+m)*GXS + (8*q ^ swg) + 4]);
            gbu[0]=packhl(ga.x); gbu[1]=packhl(ga.y);
            gbu[2]=packhl(ga.z); gbu[3]=packhl(ga.w);
            gbu[4]=packhl(gc.x); gbu[5]=packhl(gc.y);
            gbu[6]=packhl(gc.z); gbu[7]=packhl(gc.w);
          }
          fb = mkfrag(gbu);
          c1 = mfma16(faAD.h, fb.h, c1);
          c1 = mfma16(faAD.h, fb.l, c1);
          c1 = mfma16(faAD.l, fb.h, c1);
        }
        // complete fold: vp0L[1-sel] -= corr
        {
          float* vpW = &vp0L[(1-sel)*VPW];
          #pragma unroll
          for (int reg=0; reg<4; ++reg) {
            const int h = h0 + 4*q + reg;
            vpW[m*VS + h]      -= c0[reg];
            vpW[(16+m)*VS + h] -= c1[reg];
          }
        }
        // knT(ch) transposed write: knT[h][t ^ swz(h)] = kn[t][h]
        {
          const int h2 = 2*lane;
          const int swz = ((h2>>3)&3)<<3;   // same for h2 and h2+1 (h2 even)
          #pragma unroll
          for (int r=0; r<4; ++r) {
            const int t = (wv-1)*4 + r;
            knT[h2*KTS     + (t ^ swz)] = tv[r].x;
            knT[(h2+1)*KTS + (t ^ swz)] = tv[r].y;
          }
        }
        // async kn staging: kn(ch+2) -> buf cur (pre-swizzled global src,
        // linear LDS dest). Drained by B1's implicit vmcnt(0).
        if (havn2) {
          const uint32_t* gsrc = knb + (size_t)(ch+2)*CC*Hn;
          uint32_t* ldst = &kn_p[cur*CC*KP];
          #pragma unroll
          for (int r=0; r<4; ++r) {
            const int t = (wv-1)*4 + r;
            const int sw = ((t>>3)&3)<<3;
            #pragma unroll
            for (int half=0; half<2; ++half) {
              gload_lds4(gsrc + t*Hn + ((half*64 + lane) ^ sw),
                         &ldst[t*KP + half*64]);
            }
          }
          if (tid >= 288 && tid < 320) nrm_l[((ch+2)&3)*CC + (tid-288)] = pfn;
        }
      }
      __syncthreads();                     // B1
    }
  } else if (wv <= 10) {
    // ========================= GxT loop =========================
    const int tj = wv - 9;
    #pragma unroll 1
    for (int ch=0; ch<NCH; ++ch) {
      const int cur = ch&1, nx1 = (ch+1)&1;
      const uint32_t* knc = &kn_p[cur*CC*KP];
      const uint32_t* knN = &kn_p[nx1*CC*KP];
      const bool havn = (ch+1 < NCH);

      if (havn) {
        #pragma unroll
        for (int ts=0; ts<2; ++ts) {
          const int ra = 16*tj+m, rb = 16*ts+m;
          const int swa = ((ra>>3)&3)<<3, swb = ((rb>>3)&3)<<3;
          f32x4 g4 = (f32x4){0.f,0.f,0.f,0.f};
          #pragma unroll
          for (int kk=0; kk<4; ++kk) {
            uint32_t ua[8], ub[8];
            ld8(&knN[ra*KP + ((32*kk + 8*q) ^ swa)], ua);
            ld8(&knc[rb*KP + ((32*kk + 8*q) ^ swb)], ub);
            FragHL fa = mkfrag(ua), fb = mkfrag(ub);
            g4 = mfma16(fa.h, fb.h, g4);
            g4 = mfma16(fa.h, fb.l, g4);
            g4 = mfma16(fa.l, fb.h, g4);
          }
          // write with per-row swizzle: col' = col ^ 8*(row&3), row&3 == reg
          #pragma unroll
          for (int reg=0; reg<4; ++reg)
            GxT[(16*tj + 4*q + reg)*GXS + ((16*ts + m) ^ (reg<<3))] = g4[reg];
        }
      }
      __syncthreads();                     // B2
      if (ch==NCH-1) break;
      __syncthreads();                     // B1
    }
  } else {
    // ========================= Gram loop =========================
    #pragma unroll 1
    for (int ch=0; ch<NCH; ++ch) {
      const int nx1 = (ch+1)&1;
      const int sel = ch & 1;
      const uint32_t* knN = &kn_p[nx1*CC*KP];
      const bool havn = (ch+1 < NCH);

      if (havn) {
        #pragma unroll
        for (int gi=0; gi<3; ++gi) {        // (0,0),(0,1)+T,(1,1)
          const int ti = (gi==2) ? 1 : 0;
          const int si = (gi==0) ? 0 : 1;
          const int ra = 16*ti+m, rb = 16*si+m;
          const int swa = ((ra>>3)&3)<<3, swb = ((rb>>3)&3)<<3;
          f32x4 g4 = (f32x4){0.f,0.f,0.f,0.f};
          #pragma unroll
          for (int kk=0; kk<4; ++kk) {
            uint32_t ua[8], ub[8];
            ld8(&knN[ra*KP + ((32*kk + 8*q) ^ swa)], ua);
            ld8(&knN[rb*KP + ((32*kk + 8*q) ^ swb)], ub);
            FragHL fa = mkfrag(ua), fb = mkfrag(ub);
            g4 = mfma16(fa.h, fb.h, g4);
            g4 = mfma16(fa.h, fb.l, g4);
            g4 = mfma16(fa.l, fb.h, g4);
          }
          float* GtW = &Gt[(1-sel)*CC*GS];
          #pragma unroll
          for (int reg=0; reg<4; ++reg)
            GtW[(16*ti + 4*q + reg)*GS + 16*si + m] = g4[reg];
          if (gi==1) {
            #pragma unroll
            for (int reg=0; reg<4; ++reg)
              GtW[(16*si + m)*GS + 16*ti + 4*q + reg] = g4[reg];
          }
        }
      }
      __syncthreads();                     // B2
      if (ch==NCH-1) break;
      __syncthreads();                     // B1
    }
  }
}

// ---------------------------------------------------------------------------
// Phase 3a: o1 = read @ rp_w^T + rp_b
// ---------------------------------------------------------------------------
__global__ __launch_bounds__(128) void p3a(
    const float* __restrict__ read_ws, const float* __restrict__ rp_w,
    const float* __restrict__ rp_b, float* __restrict__ o1_ws)
{
  __shared__ float rd[128];
  const int b = blockIdx.x, t = threadIdx.x;
  rd[t] = read_ws[b*Hn + t];
  __syncthreads();
  float acc = rp_b[t];
  const float* wr = rp_w + t*Hn;
  #pragma unroll 4
  for (int i = 0; i < Hn; ++i) acc += rd[i]*wr[i];
  o1_ws[b*Hn + t] = acc;
}

// ---------------------------------------------------------------------------
// Phase 3b: out = o1 @ out_w^T + out_b
// ---------------------------------------------------------------------------
__global__ __launch_bounds__(256) void p3b(
    const float* __restrict__ o1_ws, const float* __restrict__ out_w,
    const float* __restrict__ out_b, float* __restrict__ out)
{
  __shared__ __align__(16) float o1[8192];       // [64][128]
  const int tid = threadIdx.x;
  #pragma unroll
  for (int c = 0; c < 32; ++c) o1[c*256+tid] = o1_ws[c*256+tid];
  __syncthreads();
  const int v = blockIdx.x*256 + tid;            // 125*256 == 32000
  float acc[64];
  const float ob = out_b[v];
  #pragma unroll
  for (int bb = 0; bb < 64; ++bb) acc[bb] = ob;
  const float4* wrow = reinterpret_cast<const float4*>(out_w + (size_t)v*Hn);
  #pragma unroll 1
  for (int r4 = 0; r4 < 32; ++r4) {
    const float4 wv = wrow[r4];
    #pragma unroll
    for (int bb = 0; bb < 64; ++bb) {
      const float4 ov = *reinterpret_cast<const float4*>(&o1[bb*Hn + r4*4]);
      acc[bb] += wv.x*ov.x + wv.y*ov.y + wv.z*ov.z + wv.w*ov.w;
    }
  }
  #pragma unroll
  for (int bb = 0; bb < 64; ++bb) out[(size_t)bb*Vn + v] = acc[bb];
}

// ---------------------------------------------------------------------------
extern "C" void kernel_launch(void* const* d_in, const int* in_sizes, int n_in,
                              void* d_out, int out_size, void* d_ws, size_t ws_size,
                              hipStream_t stream)
{
  const int*   seq     = (const int*)  d_in[0];
  const float* embed_w = (const float*)d_in[1];
  const float* ff_w1   = (const float*)d_in[2];
  const float* ff_b1   = (const float*)d_in[3];
  const float* ff_w2   = (const float*)d_in[4];
  const float* ff_b2   = (const float*)d_in[5];
  const float* ln_g    = (const float*)d_in[6];
  const float* ln_b    = (const float*)d_in[7];
  const float* kp_w    = (const float*)d_in[8];
  const float* rp_w    = (const float*)d_in[9];
  const float* rp_b    = (const float*)d_in[10];
  const float* out_w   = (const float*)d_in[11];
  const float* out_b   = (const float*)d_in[12];

  float* ws          = (float*)d_ws;
  uint32_t* knp_all  = (uint32_t*)ws;                 // B*L*H u32 (packed hi/lo)
  float* norm_all    = ws + (size_t)Bn*Ln*Hn;         // B*L
  float* read_ws     = norm_all + (size_t)Bn*Ln;      // B*H
  float* o1_ws       = read_ws + Bn*Hn;               // B*H
  uint32_t* wp       = (uint32_t*)(o1_ws + Bn*Hn);    // 81920 u32 packed weights

  p0_pack<<<dim3(160), dim3(256), 0, stream>>>(ff_w1, ff_w2, kp_w, wp);
  p1_fused<<<dim3(2048), dim3(256), 0, stream>>>(
      seq, embed_w, wp, ff_b1, ff_b2, ln_g, ln_b, knp_all, norm_all);
  p2_scan<<<dim3(64), dim3(768), 0, stream>>>(knp_all, norm_all, read_ws);
  p3a<<<dim3(64), dim3(128), 0, stream>>>(read_ws, rp_w, rp_b, o1_ws);
  p3b<<<dim3(125), dim3(256), 0, stream>>>(o1_ws, out_w, out_b, (float*)d_out);
}